// Round 2
// baseline (88.596 us; speedup 1.0000x reference)
//
#include <hip/hip_runtime.h>

#define NB    512
#define NC    128
#define HW    49      // 7*7
#define FEAT  21609   // 21*21*7*7
#define CHW   6272    // NC*HW
#define NV4   1568    // CHW/4
#define TSTR  132     // transposed row stride in floats: 16B-aligned (132*4=528=33*16),
                      // banks (132%32=4): lane cq -> bank 4*(ij+cq)%32, ~2-way = free

// prefix sums of parity-run counts: S[i] = sum_{i'<i} (4 - (i'&1))
__constant__ int c_S[7] = {0, 4, 7, 11, 14, 18, 21};

__global__ __launch_bounds__(256) void corr_head_kernel(
    const float* __restrict__ patch1,
    const float* __restrict__ patch2,
    const float* __restrict__ w_bbox,
    const float* __restrict__ b_bbox,
    float* __restrict__ out)
{
    __shared__ float  s1t[HW * TSTR];  // p1 transposed [ij][c], 25.9 KB
    __shared__ float  s2t[HW * TSTR];  // p2 transposed [kl][c], 25.9 KB
    __shared__ float4 s_w[625];        // packed head weights, grouped by ij, 10 KB
    __shared__ float  s_red[16];

    const int tid = threadIdx.x;
    const int b   = blockIdx.x;

    // ---- build packed weight table: one thread per ij, nested same-parity (i2,j2) ----
    // pair order within group: i2 outer (stride 2), j2 inner (stride 2) — must match main loop
    if (tid < 49) {
        int i  = tid / 7, j = tid - 7 * i;
        int ci = 4 - (i & 1);
        int n  = c_S[i] * 25 + ci * c_S[j];
        for (int i2 = (i & 1); i2 < 7; i2 += 2) {
            for (int j2 = (j & 1); j2 < 7; j2 += 2) {
                int p = 10 + ((i2 - i) >> 1);
                int q = 10 + ((j2 - j) >> 1);
                int f = ((p * 21 + q) * 7 + i) * 7 + j;
                s_w[n] = make_float4(w_bbox[f], w_bbox[FEAT + f],
                                     w_bbox[2 * FEAT + f], w_bbox[3 * FEAT + f]);
                ++n;
            }
        }
    }

    // ---- stage patch1/patch2 transposed into LDS: coalesced f4 reads, scattered b32 writes ----
    const float4* g1 = (const float4*)(patch1 + (size_t)b * CHW);
    const float4* g2 = (const float4*)(patch2 + (size_t)b * CHW);
    for (int t = tid; t < NV4; t += 256) {
        float4 v = g1[t];
        int e = t * 4;  // flat = c*49 + ij
        #pragma unroll
        for (int k = 0; k < 4; ++k) {
            int ee = e + k;
            int c  = ee / 49;
            int ij = ee - 49 * c;
            s1t[ij * TSTR + c] = (&v.x)[k];
        }
    }
    for (int t = tid; t < NV4; t += 256) {
        float4 v = g2[t];
        int e = t * 4;
        #pragma unroll
        for (int k = 0; k < 4; ++k) {
            int ee = e + k;
            int c  = ee / 49;
            int ij = ee - 49 * c;
            s2t[ij * TSTR + c] = (&v.x)[k];
        }
    }
    __syncthreads();

    // ---- main loop: thread (p, cq) handles ij = p, p+8, ... and channels 4cq..4cq+3 ----
    const int p  = tid >> 5;
    const int co = (tid & 31) * 4;
    float a0 = 0.f, a1 = 0.f, a2 = 0.f, a3 = 0.f;

    for (int ij = p; ij < 49; ij += 8) {
        int i = ij / 7, j = ij - 7 * i;
        const float4 f1 = *(const float4*)(s1t + ij * TSTR + co);
        int ci = 4 - (i & 1);
        int n  = c_S[i] * 25 + ci * c_S[j];
        for (int i2 = (i & 1); i2 < 7; i2 += 2) {
            const float* rowb = s2t + (i2 * 7) * TSTR + co;
            for (int j2 = (j & 1); j2 < 7; j2 += 2) {
                const float4 f2 = *(const float4*)(rowb + j2 * TSTR);
                float4 w4 = s_w[n];
                ++n;
                float s = f1.x * f2.x + f1.y * f2.y + f1.z * f2.z + f1.w * f2.w;
                a0 = fmaf(s, w4.x, a0);
                a1 = fmaf(s, w4.y, a1);
                a2 = fmaf(s, w4.z, a2);
                a3 = fmaf(s, w4.w, a3);
            }
        }
    }

    // ---- reduce 256 threads -> 4 outputs ----
    for (int off = 32; off > 0; off >>= 1) {
        a0 += __shfl_down(a0, off, 64);
        a1 += __shfl_down(a1, off, 64);
        a2 += __shfl_down(a2, off, 64);
        a3 += __shfl_down(a3, off, 64);
    }
    if ((tid & 63) == 0) {
        int w = tid >> 6;
        s_red[w * 4 + 0] = a0;
        s_red[w * 4 + 1] = a1;
        s_red[w * 4 + 2] = a2;
        s_red[w * 4 + 3] = a3;
    }
    __syncthreads();
    if (tid < 4) {
        float r = s_red[tid] + s_red[4 + tid] + s_red[8 + tid] + s_red[12 + tid];
        out[b * 4 + tid] = r + b_bbox[tid];
    }
}

extern "C" void kernel_launch(void* const* d_in, const int* in_sizes, int n_in,
                              void* d_out, int out_size, void* d_ws, size_t ws_size,
                              hipStream_t stream) {
    const float* patch1 = (const float*)d_in[0];
    const float* patch2 = (const float*)d_in[1];
    const float* w_bbox = (const float*)d_in[2];
    const float* b_bbox = (const float*)d_in[3];
    float* out = (float*)d_out;
    corr_head_kernel<<<dim3(NB), dim3(256), 0, stream>>>(patch1, patch2, w_bbox, b_bbox, out);
}

// Round 3
// 80.649 us; speedup vs baseline: 1.0985x; 1.0985x over previous
//
#include <hip/hip_runtime.h>

#define NB    512
#define FEAT  21609   // 21*21*7*7
#define CHW   6272    // 128*49
#define NV4   1568    // CHW/4
#define PLANE 5120    // 128 channels * 40-float padded block per parity class

__device__ __forceinline__ unsigned short f2bf(float x) {
    unsigned u = __float_as_uint(x);
    u += 0x7fffu + ((u >> 16) & 1u);   // round-to-nearest-even
    return (unsigned short)(u >> 16);
}
__device__ __forceinline__ float bf2f(unsigned short h) {
    return __uint_as_float((unsigned)h << 16);
}

__global__ __launch_bounds__(256) void corr_head_kernel(
    const float* __restrict__ patch1,
    const float* __restrict__ patch2,
    const float* __restrict__ w_bbox,
    const float* __restrict__ b_bbox,
    float* __restrict__ out)
{
    // p2 split by j2-parity: value p2[c, 7*i2 + 2*u + jp] at s2p[jp*PLANE + c*40 + i2*4 + u]
    // c-block is 40 floats: rows i2=0..6 occupy [0,28), dummy i2=7 row [28,32) zeroed, [32,40) pad.
    __shared__ __align__(16) unsigned short s1b[CHW];   // p1 as bf16, [c][ij], 12544 B
    __shared__ __align__(16) float          s2p[2 * PLANE];  // 40960 B
    __shared__ __align__(16) ushort4        s_wq[784];  // bf16 w4, idx (4t+u)*49+ij, 6272 B
    __shared__ float s_red[16];

    const int tid = threadIdx.x;
    const int b   = blockIdx.x;

    // ---- zero dummy-readable slots ----
    for (int n = tid; n < 1024; n += 256) {        // i2=7 dummy row of every (jp,c) block
        int jp = n >> 9, c = (n >> 2) & 127, u = n & 3;
        s2p[jp * PLANE + c * 40 + 28 + u] = 0.f;
    }
    for (int n = tid; n < 896; n += 256) {         // odd-class j2=7 dummy column
        int c = n / 7, i2 = n - 7 * c;
        s2p[PLANE + c * 40 + i2 * 4 + 3] = 0.f;
    }

    // ---- stage p1 -> bf16 LDS (coalesced f4 load, b64 store) ----
    const float4* g1 = (const float4*)(patch1 + (size_t)b * CHW);
    for (int t = tid; t < NV4; t += 256) {
        float4 v = g1[t];
        ((ushort4*)s1b)[t] = make_ushort4(f2bf(v.x), f2bf(v.y), f2bf(v.z), f2bf(v.w));
    }

    // ---- stage p2 -> parity-split layout (scatter b32, ~2-way banks) ----
    const float4* g2 = (const float4*)(patch2 + (size_t)b * CHW);
    for (int t = tid; t < NV4; t += 256) {
        float4 v = g2[t];
        int e = t * 4;
        int c = e / 49;
        int r = e - 49 * c;
        #pragma unroll
        for (int k = 0; k < 4; ++k) {
            int i2 = (r * 37) >> 8;     // r/7 for r<49
            int j2 = r - 7 * i2;
            s2p[(j2 & 1) * PLANE + c * 40 + i2 * 4 + (j2 >> 1)] = (&v.x)[k];
            if (++r == 49) { r = 0; ++c; }
        }
    }

    // ---- build bf16 weight table: entry (t,u,ij) = w4 for pair (i2=(i&1)+2t, j2=(j&1)+2u) ----
    for (int n = tid; n < 784; n += 256) {
        int ij = n % 49, tu = n / 49;
        int t = tu >> 2, u = tu & 3;
        int i = ij / 7, j = ij - 7 * i;
        int i2 = (i & 1) + 2 * t, j2 = (j & 1) + 2 * u;
        ushort4 wq = make_ushort4(0, 0, 0, 0);
        if (i2 < 7 && j2 < 7) {
            int p = 10 + ((i2 - i) >> 1);
            int q = 10 + ((j2 - j) >> 1);
            int f = ((p * 21 + q) * 7 + i) * 7 + j;
            wq = make_ushort4(f2bf(w_bbox[f]), f2bf(w_bbox[FEAT + f]),
                              f2bf(w_bbox[2 * FEAT + f]), f2bf(w_bbox[3 * FEAT + f]));
        }
        s_wq[n] = wq;
    }
    __syncthreads();

    // ---- main: thread (ij = tid>>2, cs = tid&3) handles c = cs+4*cc, cc<32 ----
    float a0 = 0.f, a1 = 0.f, a2 = 0.f, a3 = 0.f;
    if (tid < 196) {
        const int ij = tid >> 2, cs = tid & 3;
        const int i = ij / 7, j = ij - 7 * i;
        const float* base2 = s2p + (j & 1) * PLANE + (i & 1) * 4;  // + c*40 + 8t

        float dot[4][4];
        #pragma unroll
        for (int t = 0; t < 4; ++t)
            #pragma unroll
            for (int u = 0; u < 4; ++u) dot[t][u] = 0.f;

        #pragma unroll 2
        for (int cc = 0; cc < 32; ++cc) {
            int c = cs + 4 * cc;
            float f1 = bf2f(s1b[c * 49 + ij]);
            const float* bc = base2 + c * 40;
            #pragma unroll
            for (int t = 0; t < 4; ++t) {
                float4 f2 = *(const float4*)(bc + 8 * t);
                dot[t][0] = fmaf(f1, f2.x, dot[t][0]);
                dot[t][1] = fmaf(f1, f2.y, dot[t][1]);
                dot[t][2] = fmaf(f1, f2.z, dot[t][2]);
                dot[t][3] = fmaf(f1, f2.w, dot[t][3]);
            }
        }

        // ---- per-thread weighting (w amortized over 32 channels) ----
        #pragma unroll
        for (int t = 0; t < 4; ++t)
            #pragma unroll
            for (int u = 0; u < 4; ++u) {
                ushort4 wq = s_wq[(4 * t + u) * 49 + ij];
                float d = dot[t][u];
                a0 = fmaf(d, bf2f(wq.x), a0);
                a1 = fmaf(d, bf2f(wq.y), a1);
                a2 = fmaf(d, bf2f(wq.z), a2);
                a3 = fmaf(d, bf2f(wq.w), a3);
            }
    }

    // ---- reduce 256 threads -> 4 outputs ----
    for (int off = 32; off > 0; off >>= 1) {
        a0 += __shfl_down(a0, off, 64);
        a1 += __shfl_down(a1, off, 64);
        a2 += __shfl_down(a2, off, 64);
        a3 += __shfl_down(a3, off, 64);
    }
    if ((tid & 63) == 0) {
        int w = tid >> 6;
        s_red[w * 4 + 0] = a0;
        s_red[w * 4 + 1] = a1;
        s_red[w * 4 + 2] = a2;
        s_red[w * 4 + 3] = a3;
    }
    __syncthreads();
    if (tid < 4) {
        float r = s_red[tid] + s_red[4 + tid] + s_red[8 + tid] + s_red[12 + tid];
        out[b * 4 + tid] = r + b_bbox[tid];
    }
}

extern "C" void kernel_launch(void* const* d_in, const int* in_sizes, int n_in,
                              void* d_out, int out_size, void* d_ws, size_t ws_size,
                              hipStream_t stream) {
    const float* patch1 = (const float*)d_in[0];
    const float* patch2 = (const float*)d_in[1];
    const float* w_bbox = (const float*)d_in[2];
    const float* b_bbox = (const float*)d_in[3];
    float* out = (float*)d_out;
    corr_head_kernel<<<dim3(NB), dim3(256), 0, stream>>>(patch1, patch2, w_bbox, b_bbox, out);
}